// Round 1
// baseline (64805.115 us; speedup 1.0000x reference)
//
#include <hip/hip_runtime.h>
#include <math.h>

#define B_    512
#define T_    512
#define H_    256
#define DIN_  64
#define OL_   8
#define DOUT_ 64

static __device__ __forceinline__ float sigm(float x){ return 1.0f/(1.0f + expf(-x)); }

// ---------------------------------------------------------------------------
// WpT[c][d] = sum_e in_W[d][e] * enc_Wih[c][e]   (fold input proj into gates)
// c in [0,1024), d in [0,64)
// ---------------------------------------------------------------------------
__global__ void k_wpt(const float* __restrict__ inW, const float* __restrict__ Wih,
                      float* __restrict__ WpT)
{
  int gid = blockIdx.x * 256 + threadIdx.x;   // 65536 total
  int c = gid >> 6, d = gid & 63;
  const float* wr = Wih + c * H_;
  const float* ir = inW + d * H_;
  float acc = 0.f;
  #pragma unroll 4
  for (int e = 0; e < H_; e += 4) {
    float4 av = *(const float4*)(ir + e);
    float4 bv = *(const float4*)(wr + e);
    acc += av.x*bv.x + av.y*bv.y + av.z*bv.z + av.w*bv.w;
  }
  WpT[c*64 + d] = acc;
}

// bp[c] = in_b . Wih[c,:] + bih[c] + bhh[c]
__global__ void k_bp(const float* __restrict__ inb, const float* __restrict__ Wih,
                     const float* __restrict__ bih, const float* __restrict__ bhh,
                     float* __restrict__ bp)
{
  int c = blockIdx.x * 256 + threadIdx.x;   // 1024
  const float* wr = Wih + c * H_;
  float acc = bih[c] + bhh[c];
  for (int e = 0; e < H_; ++e) acc += inb[e] * wr[e];
  bp[c] = acc;
}

// dWt[k][j] = dec_Wih[row(j)][k], j<768 covering gates i,g,o (f is dead: c0=0)
__global__ void k_dwt(const float* __restrict__ dWih, float* __restrict__ dWt)
{
  int gid = blockIdx.x * 256 + threadIdx.x;   // 768*512 = 393216
  int j = gid >> 9, k = gid & 511;
  int row = (j < 256) ? j : (j + 256);        // i: 0..255 -> rows 0..255 ; g -> 512.. ; o -> 768..
  dWt[k*768 + j] = dWih[row*512 + k];
}

// ---------------------------------------------------------------------------
// Encoder LSTM, one time step. grid = (CB/32, 32). block = 256.
// block = 32 batch rows x 8 hidden units (its 4 gate columns each).
// h read from h_prev (ping-pong: avoids cross-block same-launch race).
// x-projection applied via folded WpT on the fly (no gx buffer).
// ---------------------------------------------------------------------------
__global__ __launch_bounds__(256,2) void k_enc_step(
    const float* __restrict__ x, const float* __restrict__ Whh,
    const float* __restrict__ WpT, const float* __restrict__ bp,
    const float* __restrict__ h_prev, float* __restrict__ h_next,
    float* __restrict__ c_state, float* __restrict__ enc, int t)
{
  __shared__ float ws[32][260];   // Whh rows for this block's 32 gate-cols (pad 4: conflict-free reads)
  __shared__ float wp[32][68];    // WpT rows (64 wide)
  __shared__ float bps[32];
  const int tid = threadIdx.x;
  const int b0 = blockIdx.x * 32;
  const int ug = blockIdx.y;      // units ug*8 .. ug*8+7
  for (int f = tid; f < 32*64; f += 256) {
    int c = f >> 6, k4 = f & 63;
    int grow = ((c >> 3) << 8) + (ug << 3) + (c & 7);  // gate*256 + unit
    *(float4*)(&ws[c][k4*4]) = *(const float4*)(Whh + (long)grow*H_ + k4*4);
  }
  for (int f = tid; f < 32*16; f += 256) {
    int c = f >> 4, d4 = f & 15;
    int grow = ((c >> 3) << 8) + (ug << 3) + (c & 7);
    *(float4*)(&wp[c][d4*4]) = *(const float4*)(WpT + grow*64 + d4*4);
  }
  if (tid < 32) {
    int grow = ((tid >> 3) << 8) + (ug << 3) + (tid & 7);
    bps[tid] = bp[grow];
  }
  __syncthreads();
  const int rg = tid >> 3, cg = tid & 7;   // row rg, unit cg
  const int b = b0 + rg;
  float acc[4] = {0.f,0.f,0.f,0.f};        // i,f,g,o
  const float* hrow = h_prev + b*H_;       // 8 lanes share addr -> broadcast; 8 rows/wave in L1
  #pragma unroll 4
  for (int k4 = 0; k4 < 64; ++k4) {
    float4 av = *(const float4*)(hrow + k4*4);
    #pragma unroll
    for (int j = 0; j < 4; ++j) {
      float4 wv = *(const float4*)(&ws[j*8+cg][k4*4]);
      acc[j] += av.x*wv.x + av.y*wv.y + av.z*wv.z + av.w*wv.w;
    }
  }
  const float* xrow = x + ((long)b*T_ + t)*DIN_;
  #pragma unroll 4
  for (int d4 = 0; d4 < 16; ++d4) {
    float4 av = *(const float4*)(xrow + d4*4);
    #pragma unroll
    for (int j = 0; j < 4; ++j) {
      float4 wv = *(const float4*)(&wp[j*8+cg][d4*4]);
      acc[j] += av.x*wv.x + av.y*wv.y + av.z*wv.z + av.w*wv.w;
    }
  }
  const int u = (ug << 3) + cg;
  const int idx = b*H_ + u;
  float gi = acc[0] + bps[cg];
  float gf = acc[1] + bps[8+cg];
  float gg = acc[2] + bps[16+cg];
  float go = acc[3] + bps[24+cg];
  float cn = sigm(gf)*c_state[idx] + sigm(gi)*tanhf(gg);
  float hn = sigm(go)*tanhf(cn);
  c_state[idx] = cn;
  h_next[idx]  = hn;
  enc[((long)b*T_ + t)*H_ + u] = hn;
}

// ---------------------------------------------------------------------------
// Row-block GEMM: C[M,256] = act( A[M,256] @ W[256,256] + bias ), M = grid*32.
// A rows fully staged in LDS before compute -> safe in-place (C may alias A).
// FUSE==1: A-element = tanh(A + us[row/512]) (attention input fusion).
// ---------------------------------------------------------------------------
template<int FUSE>
__global__ __launch_bounds__(256,2) void k_gemm_rb(
    const float* __restrict__ A, const float* __restrict__ W,
    const float* __restrict__ bias, float* __restrict__ C,
    const float* __restrict__ us, int relu)
{
  __shared__ float As[32][256];   // 32 KB  (reads are 2-addr broadcast: no pad needed)
  __shared__ float Bs[16][256];   // 16 KB  (reads are lane-contiguous b128)
  const int tid = threadIdx.x;
  const long m0 = (long)blockIdx.x * 32;
  for (int f = tid; f < 32*64; f += 256) {
    int r = f >> 6, k4 = f & 63;
    float4 v = *(const float4*)(A + (m0 + r)*H_ + k4*4);
    if (FUSE) {
      const float* usb = us + ((int)(m0 >> 9) << 8);   // all 32 rows share one b
      float4 u4 = *(const float4*)(usb + k4*4);
      v.x = tanhf(v.x + u4.x); v.y = tanhf(v.y + u4.y);
      v.z = tanhf(v.z + u4.z); v.w = tanhf(v.w + u4.w);
    }
    *(float4*)(&As[r][k4*4]) = v;
  }
  float acc[4][8];
  #pragma unroll
  for (int i = 0; i < 4; ++i)
    #pragma unroll
    for (int j = 0; j < 8; ++j) acc[i][j] = 0.f;
  const int tr = tid >> 5, tc = tid & 31;   // rows tr*4..+3, cols {tc*4..+3, 128+tc*4..+3}
  for (int s16 = 0; s16 < 16; ++s16) {
    __syncthreads();
    for (int f = tid; f < 16*64; f += 256) {
      int k = f >> 6, k4 = f & 63;
      *(float4*)(&Bs[k][k4*4]) = *(const float4*)(W + (long)(s16*16 + k)*H_ + k4*4);
    }
    __syncthreads();
    #pragma unroll
    for (int kk = 0; kk < 16; ++kk) {
      float4 b0 = *(const float4*)(&Bs[kk][tc*4]);
      float4 b1 = *(const float4*)(&Bs[kk][128 + tc*4]);
      #pragma unroll
      for (int i = 0; i < 4; ++i) {
        float av = As[tr*4+i][s16*16+kk];
        acc[i][0] += av*b0.x; acc[i][1] += av*b0.y;
        acc[i][2] += av*b0.z; acc[i][3] += av*b0.w;
        acc[i][4] += av*b1.x; acc[i][5] += av*b1.y;
        acc[i][6] += av*b1.z; acc[i][7] += av*b1.w;
      }
    }
  }
  float4 bb0 = *(const float4*)(bias + tc*4);
  float4 bb1 = *(const float4*)(bias + 128 + tc*4);
  #pragma unroll
  for (int i = 0; i < 4; ++i) {
    long m = m0 + tr*4 + i;
    float4 o0, o1;
    o0.x = acc[i][0]+bb0.x; o0.y = acc[i][1]+bb0.y; o0.z = acc[i][2]+bb0.z; o0.w = acc[i][3]+bb0.w;
    o1.x = acc[i][4]+bb1.x; o1.y = acc[i][5]+bb1.y; o1.z = acc[i][6]+bb1.z; o1.w = acc[i][7]+bb1.w;
    if (relu) {
      o0.x = fmaxf(o0.x,0.f); o0.y = fmaxf(o0.y,0.f); o0.z = fmaxf(o0.z,0.f); o0.w = fmaxf(o0.w,0.f);
      o1.x = fmaxf(o1.x,0.f); o1.y = fmaxf(o1.y,0.f); o1.z = fmaxf(o1.z,0.f); o1.w = fmaxf(o1.w,0.f);
    }
    *(float4*)(C + m*H_ + tc*4)       = o0;
    *(float4*)(C + m*H_ + 128 + tc*4) = o1;
  }
}

// e[m] = act[m,:] . vWl + vbl      one wave per row, grid-stride
__global__ __launch_bounds__(256,4) void k_e_final(
    const float* __restrict__ act, const float* __restrict__ vWl,
    const float* __restrict__ vbl, float* __restrict__ e, int M)
{
  const int tid = threadIdx.x;
  const int lane = tid & 63;
  const int w = (blockIdx.x << 2) + (tid >> 6);
  const int nw = gridDim.x << 2;
  float4 vl = *(const float4*)(vWl + lane*4);
  float vb = vbl[0];
  for (int m = w; m < M; m += nw) {
    float4 av = *(const float4*)(act + (long)m*H_ + lane*4);
    float d = av.x*vl.x + av.y*vl.y + av.z*vl.z + av.w*vl.w;
    #pragma unroll
    for (int o = 32; o; o >>= 1) d += __shfl_xor(d, o, 64);
    if (lane == 0) e[m] = d + vb;
  }
}

// softmax over T=512 per batch row. grid = CB, block = 256.
__global__ __launch_bounds__(256,4) void k_softmax(const float* __restrict__ e, float* __restrict__ a)
{
  __shared__ float red[8];
  const int b = blockIdx.x, tid = threadIdx.x;
  const int lane = tid & 63, w = tid >> 6;
  float v0 = e[b*512 + tid], v1 = e[b*512 + 256 + tid];
  float m = fmaxf(v0, v1);
  #pragma unroll
  for (int o = 32; o; o >>= 1) m = fmaxf(m, __shfl_xor(m, o, 64));
  if (!lane) red[w] = m;
  __syncthreads();
  m = fmaxf(fmaxf(red[0], red[1]), fmaxf(red[2], red[3]));
  float x0 = expf(v0 - m), x1 = expf(v1 - m);
  float sm = x0 + x1;
  #pragma unroll
  for (int o = 32; o; o >>= 1) sm += __shfl_xor(sm, o, 64);
  if (!lane) red[4 + w] = sm;
  __syncthreads();
  float inv = 1.f / (red[4] + red[5] + red[6] + red[7]);
  a[b*512 + tid]       = x0 * inv;
  a[b*512 + 256 + tid] = x1 * inv;
}

// c_t[b,h] = sum_t a[b,t] * enc[b,t,h].  grid = CB, block = 256 (h).
__global__ __launch_bounds__(256,2) void k_ctx(const float* __restrict__ a,
    const float* __restrict__ enc, float* __restrict__ ct)
{
  __shared__ float as[512];
  const int b = blockIdx.x, tid = threadIdx.x;
  as[tid] = a[b*512 + tid];
  as[256 + tid] = a[b*512 + 256 + tid];
  __syncthreads();
  float acc = 0.f;
  const float* ep = enc + (long)b*(T_*H_) + tid;
  #pragma unroll 8
  for (int t = 0; t < 512; ++t) acc += as[t] * ep[t*H_];
  ct[b*H_ + tid] = acc;
}

// degenerate dec LSTM cell (c0=0, Whh unused, f dead):
// s_new = sig(o)*tanh( sig(i)*tanh(g) ), gates over xt=[c_t, s] (K=512)
// grid = CB/8 (8 batch rows per block), block = 256 (u).
__global__ __launch_bounds__(256,2) void k_dec_cell(
    const float* __restrict__ ct, float* __restrict__ s, const float* __restrict__ dWt,
    const float* __restrict__ bih, const float* __restrict__ bhh,
    float* __restrict__ dec, int step)
{
  __shared__ float xt[8][516];
  const int tid = threadIdx.x;
  const int b0 = blockIdx.x * 8;
  for (int f = tid; f < 8*128; f += 256) {
    int bb = f >> 7, k4 = f & 127;
    float4 v = (k4 < 64) ? *(const float4*)(ct + (b0+bb)*H_ + k4*4)
                         : *(const float4*)(s  + (b0+bb)*H_ + (k4-64)*4);
    *(float4*)(&xt[bb][k4*4]) = v;
  }
  __syncthreads();
  const int u = tid;
  float ai[8], ag[8], ao[8];
  #pragma unroll
  for (int bb = 0; bb < 8; ++bb) { ai[bb]=0.f; ag[bb]=0.f; ao[bb]=0.f; }
  #pragma unroll 2
  for (int k = 0; k < 512; ++k) {
    float wi = dWt[k*768 + u];
    float wg = dWt[k*768 + 256 + u];
    float wo = dWt[k*768 + 512 + u];
    #pragma unroll
    for (int bb = 0; bb < 8; ++bb) {
      float xv = xt[bb][k];
      ai[bb] += xv*wi; ag[bb] += xv*wg; ao[bb] += xv*wo;
    }
  }
  float bi = bih[u]       + bhh[u];
  float bg = bih[512 + u] + bhh[512 + u];
  float bo = bih[768 + u] + bhh[768 + u];
  #pragma unroll
  for (int bb = 0; bb < 8; ++bb) {
    int b = b0 + bb;
    float cn = sigm(ai[bb] + bi) * tanhf(ag[bb] + bg);
    float hn = sigm(ao[bb] + bo) * tanhf(cn);
    s[b*H_ + u] = hn;                       // block-exclusive rows: safe
    dec[((long)b*OL_ + step)*H_ + u] = hn;
  }
}

// out[m,d] = dec[m,:] @ out_W + out_b.  grid = CB/2 (16 rows each), block 256.
__global__ __launch_bounds__(256,2) void k_outproj(
    const float* __restrict__ dec, const float* __restrict__ oW,
    const float* __restrict__ ob, float* __restrict__ out)
{
  const int tid = threadIdx.x;
  const int m0 = blockIdx.x * 16;
  const int d = tid & 63, rr = tid >> 6;
  float bv = ob[d];
  for (int p = 0; p < 4; ++p) {
    int m = m0 + p*4 + rr;
    const float* ar = dec + (long)m*H_;
    float acc = bv;
    #pragma unroll 4
    for (int k = 0; k < H_; ++k) acc += ar[k] * oW[k*64 + d];
    out[(long)m*64 + d] = acc;
  }
}

// ---------------------------------------------------------------------------
extern "C" void kernel_launch(void* const* d_in, const int* in_sizes, int n_in,
                              void* d_out, int out_size, void* d_ws, size_t ws_size,
                              hipStream_t stream)
{
  (void)in_sizes; (void)n_in; (void)out_size;
  const float* x    = (const float*)d_in[0];
  const float* inW  = (const float*)d_in[1];
  const float* inb  = (const float*)d_in[2];
  const float* eWih = (const float*)d_in[3];
  const float* eWhh = (const float*)d_in[4];
  const float* ebih = (const float*)d_in[5];
  const float* ebhh = (const float*)d_in[6];
  const float* dWih = (const float*)d_in[7];
  // d_in[8] = dec_Whh: dead (fresh zero state per decode step)
  const float* dbih = (const float*)d_in[9];
  const float* dbhh = (const float*)d_in[10];
  const float* wWs  = (const float*)d_in[11];
  const float* wbs  = (const float*)d_in[12];
  const float* wWl  = (const float*)d_in[13];
  const float* wbl  = (const float*)d_in[14];
  const float* uWs  = (const float*)d_in[15];
  const float* ubs  = (const float*)d_in[16];
  const float* uWl  = (const float*)d_in[17];
  const float* ubl  = (const float*)d_in[18];
  const float* vWs  = (const float*)d_in[19];
  const float* vbs  = (const float*)d_in[20];
  const float* vWl  = (const float*)d_in[21];
  const float* vbl  = (const float*)d_in[22];
  const float* oW   = (const float*)d_in[23];
  const float* ob   = (const float*)d_in[24];
  float* out = (float*)d_out;

  // --- workspace plan: per-sample independence -> chunk batch if ws is small
  const size_t avail = ws_size / 4;   // floats
  auto need = [](int cb) -> size_t {
    return 3ull*cb*T_*H_            // enc, whs, act
         + 7ull*cb*H_               // h0,h1,cst,s,u0,u1,ct
         + (size_t)cb*OL_*H_        // dec
         + 2ull*cb*T_               // e, a
         + 65536 + 1024 + 393216 + 4096;
  };
  int CB = 512;
  while (CB > 32 && need(CB) > avail) CB >>= 1;
  if (need(CB) > avail) { hipMemsetAsync(d_out, 0, (size_t)out_size*4, stream); return; }

  float* w    = (float*)d_ws;
  float* enc  = w;
  float* whs  = enc + (size_t)CB*T_*H_;
  float* act  = whs + (size_t)CB*T_*H_;
  float* h0   = act + (size_t)CB*T_*H_;
  float* h1   = h0 + (size_t)CB*H_;
  float* cst  = h1 + (size_t)CB*H_;
  float* s    = cst + (size_t)CB*H_;
  float* u0   = s   + (size_t)CB*H_;
  float* u1   = u0  + (size_t)CB*H_;
  float* ct   = u1  + (size_t)CB*H_;
  float* dec  = ct  + (size_t)CB*H_;
  float* e    = dec + (size_t)CB*OL_*H_;
  float* a    = e   + (size_t)CB*T_;
  float* WpT  = a   + (size_t)CB*T_;
  float* bp   = WpT + 65536;
  float* dWt  = bp  + 1024;

  // weight preps (chunk-invariant)
  k_wpt<<<256, 256, 0, stream>>>(inW, eWih, WpT);
  k_bp <<<4,   256, 0, stream>>>(inb, eWih, ebih, ebhh, bp);
  k_dwt<<<1536,256, 0, stream>>>(dWih, dWt);

  const dim3 blk(256);
  const int gBig = CB * 16;       // (CB*T)/32 row-blocks
  const int gUs  = CB / 32;

  for (int c0 = 0; c0 < B_; c0 += CB) {
    const float* xc = x + (size_t)c0*T_*DIN_;
    float* outc = out + (size_t)c0*OL_*DOUT_;

    hipMemsetAsync(h0, 0, 4ull*CB*H_*4, stream);   // h0,h1,cst,s contiguous

    // ---- encoder LSTM over T steps (h ping-pong)
    for (int t = 0; t < T_; ++t) {
      const float* hp = (t & 1) ? h1 : h0;
      float* hn       = (t & 1) ? h0 : h1;
      k_enc_step<<<dim3(CB/32, 32), blk, 0, stream>>>(xc, eWhh, WpT, bp, hp, hn, cst, enc, t);
    }

    // ---- whs = w_mlp(enc)  (loop-invariant)
    k_gemm_rb<0><<<gBig, blk, 0, stream>>>(enc, wWs + 0*65536, wbs + 0*256, act, nullptr, 1);
    k_gemm_rb<0><<<gBig, blk, 0, stream>>>(act, wWs + 1*65536, wbs + 1*256, act, nullptr, 1);
    k_gemm_rb<0><<<gBig, blk, 0, stream>>>(act, wWs + 2*65536, wbs + 2*256, act, nullptr, 1);
    k_gemm_rb<0><<<gBig, blk, 0, stream>>>(act, wWl, wbl, whs, nullptr, 0);

    // ---- decode loop
    for (int step = 0; step < OL_; ++step) {
      k_gemm_rb<0><<<gUs, blk, 0, stream>>>(s,  uWs + 0*65536, ubs + 0*256, u0, nullptr, 1);
      k_gemm_rb<0><<<gUs, blk, 0, stream>>>(u0, uWs + 1*65536, ubs + 1*256, u1, nullptr, 1);
      k_gemm_rb<0><<<gUs, blk, 0, stream>>>(u1, uWs + 2*65536, ubs + 2*256, u0, nullptr, 1);
      k_gemm_rb<0><<<gUs, blk, 0, stream>>>(u0, uWl, ubl, u1, nullptr, 0);   // us = u1

      k_gemm_rb<1><<<gBig, blk, 0, stream>>>(whs, vWs + 0*65536, vbs + 0*256, act, u1, 1);
      for (int l = 1; l < 7; ++l)
        k_gemm_rb<0><<<gBig, blk, 0, stream>>>(act, vWs + l*65536, vbs + l*256, act, nullptr, 1);
      k_e_final<<<2048, blk, 0, stream>>>(act, vWl, vbl, e, CB*T_);
      k_softmax<<<CB, blk, 0, stream>>>(e, a);
      k_ctx    <<<CB, blk, 0, stream>>>(a, enc, ct);
      k_dec_cell<<<CB/8, blk, 0, stream>>>(ct, s, dWt, dbih, dbhh, dec, step);
    }
    k_outproj<<<CB/2, blk, 0, stream>>>(dec, oW, ob, outc);
  }
}

// Round 2
// 44273.578 us; speedup vs baseline: 1.4637x; 1.4637x over previous
//
#include <hip/hip_runtime.h>
#include <math.h>

#define B_    512
#define T_    512
#define H_    256
#define DIN_  64
#define OL_   8
#define DOUT_ 64

typedef unsigned short u16;
typedef __attribute__((ext_vector_type(8))) short short8;   // 8 bf16 = 4 VGPR (MFMA A/B frag)
typedef __attribute__((ext_vector_type(4))) float f32x4;    // MFMA C/D frag (16x16)

static __device__ __forceinline__ float sigm(float x){ return 1.0f/(1.0f + expf(-x)); }
static __device__ __forceinline__ float bf2f(u16 h){
  unsigned u = ((unsigned)h) << 16; float f; __builtin_memcpy(&f, &u, 4); return f;
}
static __device__ __forceinline__ u16 f2bf(float f){        // RNE
  unsigned u; __builtin_memcpy(&u, &f, 4);
  u = (u + 0x7fffu + ((u >> 16) & 1u)) >> 16;
  return (u16)u;
}
static __device__ __forceinline__ void gll16(const void* g, void* l){
  __builtin_amdgcn_global_load_lds((const __attribute__((address_space(1))) void*)g,
                                   (__attribute__((address_space(3))) void*)l, 16, 0, 0);
}

// ---------------------------------------------------------------------------
// WpT[c][d] = sum_e in_W[d][e] * enc_Wih[c][e]   (fold input proj into gates)
// ---------------------------------------------------------------------------
__global__ void k_wpt(const float* __restrict__ inW, const float* __restrict__ Wih,
                      float* __restrict__ WpT)
{
  int gid = blockIdx.x * 256 + threadIdx.x;   // 65536
  int c = gid >> 6, d = gid & 63;
  const float* wr = Wih + c * H_;
  const float* ir = inW + d * H_;
  float acc = 0.f;
  #pragma unroll 4
  for (int e = 0; e < H_; e += 4) {
    float4 av = *(const float4*)(ir + e);
    float4 bv = *(const float4*)(wr + e);
    acc += av.x*bv.x + av.y*bv.y + av.z*bv.z + av.w*bv.w;
  }
  WpT[c*64 + d] = acc;
}

__global__ void k_bp(const float* __restrict__ inb, const float* __restrict__ Wih,
                     const float* __restrict__ bih, const float* __restrict__ bhh,
                     float* __restrict__ bp)
{
  int c = blockIdx.x * 256 + threadIdx.x;   // 1024
  const float* wr = Wih + c * H_;
  float acc = bih[c] + bhh[c];
  for (int e = 0; e < H_; ++e) acc += inb[e] * wr[e];
  bp[c] = acc;
}

// dWt[k][j], j<768 covering dec gates i,g,o (f dead: c0=0)
__global__ void k_dwt(const float* __restrict__ dWih, float* __restrict__ dWt)
{
  int gid = blockIdx.x * 256 + threadIdx.x;   // 393216
  int j = gid >> 9, k = gid & 511;
  int row = (j < 256) ? j : (j + 256);
  dWt[k*768 + j] = dWih[row*512 + k];
}

// W[k][n] fp32 -> Bt_hi[n][k], Bt_lo[n][k] bf16 (transposed + hi/lo split)
__global__ void k_wprep(const float* __restrict__ W, u16* __restrict__ bt)
{
  int gid = blockIdx.x * 256 + threadIdx.x;   // 65536
  int n = gid >> 8, k = gid & 255;
  float w = W[k*256 + n];
  u16 h = f2bf(w);
  bt[n*256 + k] = h;
  bt[65536 + n*256 + k] = f2bf(w - bf2f(h));
}

// ---------------------------------------------------------------------------
// Encoder LSTM, one time step (unchanged from r1).
// ---------------------------------------------------------------------------
__global__ __launch_bounds__(256,2) void k_enc_step(
    const float* __restrict__ x, const float* __restrict__ Whh,
    const float* __restrict__ WpT, const float* __restrict__ bp,
    const float* __restrict__ h_prev, float* __restrict__ h_next,
    float* __restrict__ c_state, float* __restrict__ enc, int t)
{
  __shared__ float ws[32][260];
  __shared__ float wp[32][68];
  __shared__ float bps[32];
  const int tid = threadIdx.x;
  const int b0 = blockIdx.x * 32;
  const int ug = blockIdx.y;
  for (int f = tid; f < 32*64; f += 256) {
    int c = f >> 6, k4 = f & 63;
    int grow = ((c >> 3) << 8) + (ug << 3) + (c & 7);
    *(float4*)(&ws[c][k4*4]) = *(const float4*)(Whh + (long)grow*H_ + k4*4);
  }
  for (int f = tid; f < 32*16; f += 256) {
    int c = f >> 4, d4 = f & 15;
    int grow = ((c >> 3) << 8) + (ug << 3) + (c & 7);
    *(float4*)(&wp[c][d4*4]) = *(const float4*)(WpT + grow*64 + d4*4);
  }
  if (tid < 32) {
    int grow = ((tid >> 3) << 8) + (ug << 3) + (tid & 7);
    bps[tid] = bp[grow];
  }
  __syncthreads();
  const int rg = tid >> 3, cg = tid & 7;
  const int b = b0 + rg;
  float acc[4] = {0.f,0.f,0.f,0.f};
  const float* hrow = h_prev + b*H_;
  #pragma unroll 4
  for (int k4 = 0; k4 < 64; ++k4) {
    float4 av = *(const float4*)(hrow + k4*4);
    #pragma unroll
    for (int j = 0; j < 4; ++j) {
      float4 wv = *(const float4*)(&ws[j*8+cg][k4*4]);
      acc[j] += av.x*wv.x + av.y*wv.y + av.z*wv.z + av.w*wv.w;
    }
  }
  const float* xrow = x + ((long)b*T_ + t)*DIN_;
  #pragma unroll 4
  for (int d4 = 0; d4 < 16; ++d4) {
    float4 av = *(const float4*)(xrow + d4*4);
    #pragma unroll
    for (int j = 0; j < 4; ++j) {
      float4 wv = *(const float4*)(&wp[j*8+cg][d4*4]);
      acc[j] += av.x*wv.x + av.y*wv.y + av.z*wv.z + av.w*wv.w;
    }
  }
  const int u = (ug << 3) + cg;
  const int idx = b*H_ + u;
  float gi = acc[0] + bps[cg];
  float gf = acc[1] + bps[8+cg];
  float gg = acc[2] + bps[16+cg];
  float go = acc[3] + bps[24+cg];
  float cn = sigm(gf)*c_state[idx] + sigm(gi)*tanhf(gg);
  float hn = sigm(go)*tanhf(cn);
  c_state[idx] = cn;
  h_next[idx]  = hn;
  enc[((long)b*T_ + t)*H_ + u] = hn;
}

// ---------------------------------------------------------------------------
// MFMA GEMM, fp32-emulated via bf16 hi/lo split: C = act(A @ W + bias).
// Block: 128 rows x 256 cols, 4 waves (2x2) of 64x128 (4x8 16x16 frags).
// K=256 in 8 slabs of 32. LDS 48KB fragment-linear; staged via
// global_load_lds w=16 with pre-permuted per-lane source (IN_MODE 0).
// IN_MODE: 0 = A is (Ahi,Alo) bf16 pair; 1 = A is fp32 (split in staging);
//          2 = A = tanh((Ahi+Alo) + us[row>>9]) (attention fusion).
// OUT_FP32: 1 = write Cf fp32; 0 = write (Chi,Clo) pair. In-place safe.
// ---------------------------------------------------------------------------
template<int IN_MODE, int OUT_FP32>
__global__ __launch_bounds__(256,2) void k_mfma(
    const u16* __restrict__ Ahi, const u16* __restrict__ Alo,
    const float* __restrict__ Af, const float* __restrict__ usp,
    const u16* __restrict__ Bhi, const u16* __restrict__ Blo,
    const float* __restrict__ bias,
    u16* __restrict__ Chi, u16* __restrict__ Clo, float* __restrict__ Cf,
    int relu)
{
  __shared__ u16 lds[24576];  // Ah[0,4096) Al[4096,8192) Bh[8192,16384) Bl[16384,24576)
  const int tid = threadIdx.x, l = tid & 63, wid = tid >> 6;
  const int wr = wid >> 1, wc = wid & 1;
  const int lr = l & 15, lk = l >> 4;
  const long m0 = (long)blockIdx.x * 128;

  f32x4 acc[4][8];
  #pragma unroll
  for (int r = 0; r < 4; ++r)
    #pragma unroll
    for (int c = 0; c < 8; ++c) acc[r][c] = (f32x4){0.f,0.f,0.f,0.f};

  // ---- staging descriptors (all arrays static-indexed via full unroll)
  const u16* sp[12]; int so[12];
  const u16* bsp[8]; int bso[8];
  const float* afp[2];
  const u16 *whp[2], *wlp[2];
  const float* up = nullptr;
  int art[2];

  if (IN_MODE == 0) {
    #pragma unroll
    for (int i = 0; i < 12; ++i) {
      int id = wid*12 + i;
      if (id < 16) {                      // A chunks: arr(hi/lo) x rt(0..7)
        int arr = id >> 3, rt = id & 7;
        sp[i] = (arr ? Alo : Ahi) + (m0 + rt*16 + lr)*256 + lk*8;
        so[i] = arr*4096 + rt*512;
      } else {                            // B chunks: arr x ct(0..15)
        int j = id - 16, arr = j >> 4, ct = j & 15;
        sp[i] = (arr ? Blo : Bhi) + (ct*16 + lr)*256 + lk*8;
        so[i] = 8192 + arr*8192 + ct*512;
      }
    }
  } else {
    #pragma unroll
    for (int i = 0; i < 8; ++i) {
      int id = wid*8 + i, arr = id >> 4, ct = id & 15;
      bsp[i] = (arr ? Blo : Bhi) + (ct*16 + lr)*256 + lk*8;
      bso[i] = 8192 + arr*8192 + ct*512;
    }
    #pragma unroll
    for (int i = 0; i < 2; ++i) {
      int rt = wid*2 + i;
      art[i] = rt;
      long row = m0 + rt*16 + lr;
      if (IN_MODE == 1) { afp[i] = Af + row*256 + lk*8; }
      else { whp[i] = Ahi + row*256 + lk*8; wlp[i] = Alo + row*256 + lk*8; }
    }
    if (IN_MODE == 2) up = usp + (m0 >> 9)*256 + lk*8;
  }

  for (int s = 0; s < 8; ++s) {
    if (s) __syncthreads();               // protect LDS from prior-slab readers
    if (IN_MODE == 0) {
      #pragma unroll
      for (int i = 0; i < 12; ++i) { gll16(sp[i], &lds[so[i]]); sp[i] += 32; }
    } else {
      #pragma unroll
      for (int i = 0; i < 8; ++i) { gll16(bsp[i], &lds[bso[i]]); bsp[i] += 32; }
      float v[2][8];
      if (IN_MODE == 1) {
        #pragma unroll
        for (int i = 0; i < 2; ++i) {
          float4 a0 = *(const float4*)(afp[i]);
          float4 a1 = *(const float4*)(afp[i] + 4);
          v[i][0]=a0.x; v[i][1]=a0.y; v[i][2]=a0.z; v[i][3]=a0.w;
          v[i][4]=a1.x; v[i][5]=a1.y; v[i][6]=a1.z; v[i][7]=a1.w;
          afp[i] += 32;
        }
      } else {
        float u8[8];
        {
          float4 ua = *(const float4*)(up), ub = *(const float4*)(up + 4);
          u8[0]=ua.x;u8[1]=ua.y;u8[2]=ua.z;u8[3]=ua.w;
          u8[4]=ub.x;u8[5]=ub.y;u8[6]=ub.z;u8[7]=ub.w;
          up += 32;
        }
        #pragma unroll
        for (int i = 0; i < 2; ++i) {
          ushort4 h0 = *(const ushort4*)(whp[i]);
          ushort4 h1 = *(const ushort4*)(whp[i] + 4);
          ushort4 q0 = *(const ushort4*)(wlp[i]);
          ushort4 q1 = *(const ushort4*)(wlp[i] + 4);
          v[i][0] = tanhf(bf2f(h0.x)+bf2f(q0.x)+u8[0]);
          v[i][1] = tanhf(bf2f(h0.y)+bf2f(q0.y)+u8[1]);
          v[i][2] = tanhf(bf2f(h0.z)+bf2f(q0.z)+u8[2]);
          v[i][3] = tanhf(bf2f(h0.w)+bf2f(q0.w)+u8[3]);
          v[i][4] = tanhf(bf2f(h1.x)+bf2f(q1.x)+u8[4]);
          v[i][5] = tanhf(bf2f(h1.y)+bf2f(q1.y)+u8[5]);
          v[i][6] = tanhf(bf2f(h1.z)+bf2f(q1.z)+u8[6]);
          v[i][7] = tanhf(bf2f(h1.w)+bf2f(q1.w)+u8[7]);
          whp[i] += 32; wlp[i] += 32;
        }
      }
      #pragma unroll
      for (int i = 0; i < 2; ++i) {
        short8 hv, lv;
        #pragma unroll
        for (int j = 0; j < 8; ++j) {
          u16 h = f2bf(v[i][j]);
          hv[j] = (short)h;
          lv[j] = (short)f2bf(v[i][j] - bf2f(h));
        }
        *(short8*)&lds[art[i]*512 + l*8] = hv;
        *(short8*)&lds[4096 + art[i]*512 + l*8] = lv;
      }
    }
    __syncthreads();

    short8 aH[4], aL[4];
    #pragma unroll
    for (int r = 0; r < 4; ++r) {
      aH[r] = *(const short8*)&lds[(wr*4 + r)*512 + l*8];
      aL[r] = *(const short8*)&lds[4096 + (wr*4 + r)*512 + l*8];
    }
    #pragma unroll
    for (int c = 0; c < 8; ++c) {
      short8 bh = *(const short8*)&lds[8192  + (wc*8 + c)*512 + l*8];
      short8 bl = *(const short8*)&lds[16384 + (wc*8 + c)*512 + l*8];
      #pragma unroll
      for (int r = 0; r < 4; ++r) {
        acc[r][c] = __builtin_amdgcn_mfma_f32_16x16x32_bf16(aH[r], bh, acc[r][c], 0, 0, 0);
        acc[r][c] = __builtin_amdgcn_mfma_f32_16x16x32_bf16(aL[r], bh, acc[r][c], 0, 0, 0);
        acc[r][c] = __builtin_amdgcn_mfma_f32_16x16x32_bf16(aH[r], bl, acc[r][c], 0, 0, 0);
      }
    }
  }

  // ---- epilogue: bias + relu + store (C layout: col=lane&15, row=lk*4+reg)
  #pragma unroll
  for (int c = 0; c < 8; ++c) {
    int col = (wc*8 + c)*16 + lr;
    float bv = bias[col];
    #pragma unroll
    for (int r = 0; r < 4; ++r) {
      long rowb = m0 + (wr*4 + r)*16 + lk*4;
      #pragma unroll
      for (int g = 0; g < 4; ++g) {
        float xv = acc[r][c][g] + bv;
        if (relu) xv = fmaxf(xv, 0.f);
        long off = (rowb + g)*256 + col;
        if (OUT_FP32) { Cf[off] = xv; }
        else {
          u16 h = f2bf(xv);
          Chi[off] = h;
          Clo[off] = f2bf(xv - bf2f(h));
        }
      }
    }
  }
}

// e[m] = (hi+lo)[m,:] . vWl + vbl
__global__ __launch_bounds__(256,4) void k_e_final(
    const u16* __restrict__ aH, const u16* __restrict__ aL,
    const float* __restrict__ vWl, const float* __restrict__ vbl,
    float* __restrict__ e, int M)
{
  const int tid = threadIdx.x, lane = tid & 63;
  const int w = (blockIdx.x << 2) + (tid >> 6);
  const int nw = gridDim.x << 2;
  float4 vl = *(const float4*)(vWl + lane*4);
  float vb = vbl[0];
  for (int m = w; m < M; m += nw) {
    ushort4 h  = *(const ushort4*)(aH + (size_t)m*256 + lane*4);
    ushort4 lo = *(const ushort4*)(aL + (size_t)m*256 + lane*4);
    float d = (bf2f(h.x)+bf2f(lo.x))*vl.x + (bf2f(h.y)+bf2f(lo.y))*vl.y
            + (bf2f(h.z)+bf2f(lo.z))*vl.z + (bf2f(h.w)+bf2f(lo.w))*vl.w;
    #pragma unroll
    for (int o2 = 32; o2; o2 >>= 1) d += __shfl_xor(d, o2, 64);
    if (lane == 0) e[m] = d + vb;
  }
}

__global__ __launch_bounds__(256,4) void k_softmax(const float* __restrict__ e, float* __restrict__ a)
{
  __shared__ float red[8];
  const int b = blockIdx.x, tid = threadIdx.x;
  const int lane = tid & 63, w = tid >> 6;
  float v0 = e[b*512 + tid], v1 = e[b*512 + 256 + tid];
  float m = fmaxf(v0, v1);
  #pragma unroll
  for (int o = 32; o; o >>= 1) m = fmaxf(m, __shfl_xor(m, o, 64));
  if (!lane) red[w] = m;
  __syncthreads();
  m = fmaxf(fmaxf(red[0], red[1]), fmaxf(red[2], red[3]));
  float x0 = expf(v0 - m), x1 = expf(v1 - m);
  float sm = x0 + x1;
  #pragma unroll
  for (int o = 32; o; o >>= 1) sm += __shfl_xor(sm, o, 64);
  if (!lane) red[4 + w] = sm;
  __syncthreads();
  float inv = 1.f / (red[4] + red[5] + red[6] + red[7]);
  a[b*512 + tid]       = x0 * inv;
  a[b*512 + 256 + tid] = x1 * inv;
}

__global__ __launch_bounds__(256,2) void k_ctx(const float* __restrict__ a,
    const float* __restrict__ enc, float* __restrict__ ct)
{
  __shared__ float as[512];
  const int b = blockIdx.x, tid = threadIdx.x;
  as[tid] = a[b*512 + tid];
  as[256 + tid] = a[b*512 + 256 + tid];
  __syncthreads();
  float acc = 0.f;
  const float* ep = enc + (long)b*(T_*H_) + tid;
  #pragma unroll 8
  for (int t = 0; t < 512; ++t) acc += as[t] * ep[t*H_];
  ct[b*H_ + tid] = acc;
}

__global__ __launch_bounds__(256,2) void k_dec_cell(
    const float* __restrict__ ct, float* __restrict__ s, const float* __restrict__ dWt,
    const float* __restrict__ bih, const float* __restrict__ bhh,
    float* __restrict__ dec, int step)
{
  __shared__ float xt[8][516];
  const int tid = threadIdx.x;
  const int b0 = blockIdx.x * 8;
  for (int f = tid; f < 8*128; f += 256) {
    int bb = f >> 7, k4 = f & 127;
    float4 v = (k4 < 64) ? *(const float4*)(ct + (b0+bb)*H_ + k4*4)
                         : *(const float4*)(s  + (b0+bb)*H_ + (k4-64)*4);
    *(float4*)(&xt[bb][k4*4]) = v;
  }
  __syncthreads();
  const int u = tid;
  float ai[8], ag[8], ao[8];
  #pragma unroll
  for (int bb = 0; bb < 8; ++bb) { ai[bb]=0.f; ag[bb]=0.f; ao[bb]=0.f; }
  #pragma unroll 2
  for (int k = 0; k < 512; ++k) {
    float wi = dWt[k*768 + u];
    float wg = dWt[k*768 + 256 + u];
    float wo = dWt[k*768 + 512 + u];
    #pragma unroll
    for (int bb = 0; bb < 8; ++bb) {
      float xv = xt[bb][k];
      ai[bb] += xv*wi; ag[bb] += xv*wg; ao[bb] += xv*wo;
    }
  }
  float bi = bih[u]       + bhh[u];
  float bg = bih[512 + u] + bhh[512 + u];
  float bo = bih[768 + u] + bhh[768 + u];
  #pragma unroll
  for (int bb = 0; bb < 8; ++bb) {
    int b = b0 + bb;
    float cn = sigm(ai[bb] + bi) * tanhf(ag[bb] + bg);
    float hn = sigm(ao[bb] + bo) * tanhf(cn);
    s[b*H_ + u] = hn;
    dec[((long)b*OL_ + step)*H_ + u] = hn;
  }
}

__global__ __launch_bounds__(256,2) void k_outproj(
    const float* __restrict__ dec, const float* __restrict__ oW,
    const float* __restrict__ ob, float* __restrict__ out)
{
  const int tid = threadIdx.x;
  const int m0 = blockIdx.x * 16;
  const int d = tid & 63, rr = tid >> 6;
  float bv = ob[d];
  for (int p = 0; p < 4; ++p) {
    int m = m0 + p*4 + rr;
    const float* ar = dec + (long)m*H_;
    float acc = bv;
    #pragma unroll 4
    for (int k = 0; k < H_; ++k) acc += ar[k] * oW[k*64 + d];
    out[(long)m*64 + d] = acc;
  }
}

// ---------------------------------------------------------------------------
extern "C" void kernel_launch(void* const* d_in, const int* in_sizes, int n_in,
                              void* d_out, int out_size, void* d_ws, size_t ws_size,
                              hipStream_t stream)
{
  (void)in_sizes; (void)n_in;
  const float* x    = (const float*)d_in[0];
  const float* inW  = (const float*)d_in[1];
  const float* inb  = (const float*)d_in[2];
  const float* eWih = (const float*)d_in[3];
  const float* eWhh = (const float*)d_in[4];
  const float* ebih = (const float*)d_in[5];
  const float* ebhh = (const float*)d_in[6];
  const float* dWih = (const float*)d_in[7];
  const float* dbih = (const float*)d_in[9];
  const float* dbhh = (const float*)d_in[10];
  const float* wWs  = (const float*)d_in[11];
  const float* wbs  = (const float*)d_in[12];
  const float* wWl  = (const float*)d_in[13];
  const float* wbl  = (const float*)d_in[14];
  const float* uWs  = (const float*)d_in[15];
  const float* ubs  = (const float*)d_in[16];
  const float* uWl  = (const float*)d_in[17];
  const float* ubl  = (const float*)d_in[18];
  const float* vWs  = (const float*)d_in[19];
  const float* vbs  = (const float*)d_in[20];
  const float* vWl  = (const float*)d_in[21];
  const float* vbl  = (const float*)d_in[22];
  const float* oW   = (const float*)d_in[23];
  const float* ob   = (const float*)d_in[24];
  float* out = (float*)d_out;

  const size_t avail = ws_size / 4;   // float units
  auto need = [](int cb) -> size_t {
    size_t ru = cb > 128 ? (size_t)cb : 128;
    return 3ull*cb*T_*H_            // enc + whs pair + act pair
         + 3ull*cb*H_               // h0,h1,cst
         + 4ull*ru*H_               // s, u0 pair, u1 pair, us
         + 1ull*cb*H_               // ct
         + (size_t)cb*OL_*H_        // dec
         + 2ull*cb*T_               // e, a
         + 65536 + 1024 + 393216    // WpT, bp, dWt
         + 15ull*65536              // weight bf16 pairs
         + 4096;
  };
  int CB = 512;
  while (CB > 32 && need(CB) > avail) CB >>= 1;
  if (need(CB) > avail) { hipMemsetAsync(d_out, 0, (size_t)out_size*4, stream); return; }
  const size_t RU = CB > 128 ? (size_t)CB : 128;

  float* w = (float*)d_ws;
  size_t o = 0;
  float* enc = w;                                               o += (size_t)CB*T_*H_;
  u16* whsH = (u16*)(w + o); u16* whsL = whsH + (size_t)CB*T_*H_; o += (size_t)CB*T_*H_;
  u16* actH = (u16*)(w + o); u16* actL = actH + (size_t)CB*T_*H_; o += (size_t)CB*T_*H_;
  float* h0  = w + o; o += (size_t)CB*H_;
  float* h1  = w + o; o += (size_t)CB*H_;
  float* cst = w + o; o += (size_t)CB*H_;
  float* s   = w + o; o += RU*H_;
  u16* u0H = (u16*)(w + o); u16* u0L = u0H + RU*H_;             o += RU*H_;
  u16* u1H = (u16*)(w + o); u16* u1L = u1H + RU*H_;             o += RU*H_;
  float* us  = w + o; o += RU*H_;
  float* ct  = w + o; o += (size_t)CB*H_;
  float* dec = w + o; o += (size_t)CB*OL_*H_;
  float* e   = w + o; o += (size_t)CB*T_;
  float* a   = w + o; o += (size_t)CB*T_;
  float* WpT = w + o; o += 65536;
  float* bp  = w + o; o += 1024;
  float* dWt = w + o; o += 393216;
  u16* wbt = (u16*)(w + o);

  // ---- weight preps (chunk-invariant)
  k_wpt<<<256, 256, 0, stream>>>(inW, eWih, WpT);
  k_bp <<<4,   256, 0, stream>>>(inb, eWih, ebih, ebhh, bp);
  k_dwt<<<1536,256, 0, stream>>>(dWih, dWt);
  const float* msrc[15] = { wWs, wWs+65536, wWs+2*65536, wWl,
                            uWs, uWs+65536, uWs+2*65536, uWl,
                            vWs, vWs+65536, vWs+2*65536, vWs+3*65536,
                            vWs+4*65536, vWs+5*65536, vWs+6*65536 };
  for (int i = 0; i < 15; ++i)
    k_wprep<<<256, 256, 0, stream>>>(msrc[i], wbt + (size_t)i*131072);

  auto BHp = [&](int m){ return (const u16*)(wbt + (size_t)m*131072); };
  auto BLp = [&](int m){ return (const u16*)(wbt + (size_t)m*131072 + 65536); };

  const int gBig = CB * 4;      // (CB*T)/128 row-tiles
  const int gU   = (int)(RU / 128);

  for (int c0 = 0; c0 < B_; c0 += CB) {
    const float* xc = x + (size_t)c0*T_*DIN_;
    float* outc = out + (size_t)c0*OL_*DOUT_;

    hipMemsetAsync(h0, 0, (3ull*CB*H_ + RU*H_)*4, stream);   // h0,h1,cst,s

    for (int t = 0; t < T_; ++t) {
      const float* hp = (t & 1) ? h1 : h0;
      float* hn       = (t & 1) ? h0 : h1;
      k_enc_step<<<dim3(CB/32, 32), 256, 0, stream>>>(xc, eWhh, WpT, bp, hp, hn, cst, enc, t);
    }

    // ---- whs = w_mlp(enc)
    k_mfma<1,0><<<gBig,256,0,stream>>>(nullptr,nullptr,enc,nullptr, BHp(0),BLp(0), wbs,     actH,actL,nullptr, 1);
    k_mfma<0,0><<<gBig,256,0,stream>>>(actH,actL,nullptr,nullptr,   BHp(1),BLp(1), wbs+256, actH,actL,nullptr, 1);
    k_mfma<0,0><<<gBig,256,0,stream>>>(actH,actL,nullptr,nullptr,   BHp(2),BLp(2), wbs+512, actH,actL,nullptr, 1);
    k_mfma<0,0><<<gBig,256,0,stream>>>(actH,actL,nullptr,nullptr,   BHp(3),BLp(3), wbl,     whsH,whsL,nullptr, 0);

    for (int step = 0; step < OL_; ++step) {
      k_mfma<1,0><<<gU,256,0,stream>>>(nullptr,nullptr,s,nullptr, BHp(4),BLp(4), ubs,     u0H,u0L,nullptr, 1);
      k_mfma<0,0><<<gU,256,0,stream>>>(u0H,u0L,nullptr,nullptr,   BHp(5),BLp(5), ubs+256, u1H,u1L,nullptr, 1);
      k_mfma<0,0><<<gU,256,0,stream>>>(u1H,u1L,nullptr,nullptr,   BHp(6),BLp(6), ubs+512, u0H,u0L,nullptr, 1);
      k_mfma<0,1><<<gU,256,0,stream>>>(u0H,u0L,nullptr,nullptr,   BHp(7),BLp(7), ubl,     nullptr,nullptr,us, 0);

      k_mfma<2,0><<<gBig,256,0,stream>>>(whsH,whsL,nullptr,us, BHp(8),BLp(8), vbs, actH,actL,nullptr, 1);
      for (int lyr = 1; lyr < 7; ++lyr)
        k_mfma<0,0><<<gBig,256,0,stream>>>(actH,actL,nullptr,nullptr, BHp(8+lyr),BLp(8+lyr), vbs+lyr*256, actH,actL,nullptr, 1);
      k_e_final<<<2048,256,0,stream>>>(actH, actL, vWl, vbl, e, CB*T_);
      k_softmax<<<CB,256,0,stream>>>(e, a);
      k_ctx    <<<CB,256,0,stream>>>(a, enc, ct);
      k_dec_cell<<<CB/8,256,0,stream>>>(ct, s, dWt, dbih, dbhh, dec, step);
    }
    k_outproj<<<CB/2,256,0,stream>>>(dec, oW, ob, outc);
  }
}

// Round 3
// 38825.864 us; speedup vs baseline: 1.6691x; 1.1403x over previous
//
#include <hip/hip_runtime.h>
#include <math.h>

#define B_    512
#define T_    512
#define H_    256
#define DIN_  64
#define OL_   8
#define DOUT_ 64

typedef unsigned short u16;
typedef unsigned int u32;
typedef __attribute__((ext_vector_type(8))) short short8;   // 8 bf16 (MFMA A/B frag)
typedef __attribute__((ext_vector_type(4))) float f32x4;    // MFMA C/D frag (16x16)

static __device__ __forceinline__ float sigm(float x){ return 1.0f/(1.0f + expf(-x)); }
static __device__ __forceinline__ float bf2f(u16 h){
  u32 u = ((u32)h) << 16; float f; __builtin_memcpy(&f, &u, 4); return f;
}
static __device__ __forceinline__ u16 f2bf(float f){        // RNE
  u32 u; __builtin_memcpy(&u, &f, 4);
  u = (u + 0x7fffu + ((u >> 16) & 1u)) >> 16;
  return (u16)u;
}
static __device__ __forceinline__ u32 packhl(float f){      // hi<<16 | lo
  u16 h = f2bf(f);
  u16 lo = f2bf(f - bf2f(h));
  return ((u32)h << 16) | (u32)lo;
}

// ---------------------------------------------------------------------------
// Weight preps
// ---------------------------------------------------------------------------
// WpT[c][d] = sum_e in_W[d][e] * enc_Wih[c][e]   (fold input proj into gates)
__global__ void k_wpt(const float* __restrict__ inW, const float* __restrict__ Wih,
                      float* __restrict__ WpT)
{
  int gid = blockIdx.x * 256 + threadIdx.x;   // 65536
  int c = gid >> 6, d = gid & 63;
  const float* wr = Wih + c * H_;
  const float* ir = inW + d * H_;
  float acc = 0.f;
  #pragma unroll 4
  for (int e = 0; e < H_; e += 4) {
    float4 av = *(const float4*)(ir + e);
    float4 bv = *(const float4*)(wr + e);
    acc += av.x*bv.x + av.y*bv.y + av.z*bv.z + av.w*bv.w;
  }
  WpT[c*64 + d] = acc;
}

// bp[c] = in_b . Wih[c,:] + bih[c] + bhh[c]
__global__ void k_bp(const float* __restrict__ inb, const float* __restrict__ Wih,
                     const float* __restrict__ bih, const float* __restrict__ bhh,
                     float* __restrict__ bp)
{
  int c = blockIdx.x * 256 + threadIdx.x;   // 1024
  const float* wr = Wih + c * H_;
  float acc = bih[c] + bhh[c];
  for (int e = 0; e < H_; ++e) acc += inb[e] * wr[e];
  bp[c] = acc;
}

// permuted bias: n -> (ug,gate,uu): bpp[n] = bp[gate*256 + ug*32 + uu]
__global__ void k_bpp(const float* __restrict__ bp, float* __restrict__ bpp)
{
  int n = blockIdx.x * 256 + threadIdx.x;   // 1024
  int ug = n >> 7, c = n & 127;
  bpp[n] = bp[(c >> 5)*256 + ug*32 + (c & 31)];
}

// dWt[k][j], j<768 covering dec gates i,g,o (f dead: c0=0)
__global__ void k_dwt(const float* __restrict__ dWih, float* __restrict__ dWt)
{
  int gid = blockIdx.x * 256 + threadIdx.x;   // 393216
  int j = gid >> 9, k = gid & 511;
  int row = (j < 256) ? j : (j + 256);
  dWt[k*768 + j] = dWih[row*512 + k];
}

// MLP weight W[k][n] (256x256 row-major, in x out) -> fragment-linear bf16 hi/lo:
// FL[arr][s][ctg][lane][j] : k = s*32 + (lane>>4)*8 + j, n = ctg*16 + (lane&15)
__global__ void k_wfl(const float* __restrict__ W, u16* __restrict__ out)
{
  int gid = blockIdx.x * 256 + threadIdx.x;   // 65536
  int k = gid & 255, n = gid >> 8;
  float v = W[k*256 + n];
  int s = k >> 5, j = k & 7;
  int lane = (((k >> 3) & 3) << 4) | (n & 15);
  int fl = ((s*16) + (n >> 4))*512 + lane*8 + j;
  u16 h = f2bf(v);
  out[fl] = h;
  out[65536 + fl] = f2bf(v - bf2f(h));
}

// Whh (1024x256) -> gate-permuted transposed fragment-linear (K=256, N=1024)
__global__ void k_whhfl(const float* __restrict__ Whh, u16* __restrict__ out)
{
  int gid = blockIdx.x * 256 + threadIdx.x;   // 262144
  int j = gid & 7, l = (gid >> 3) & 63, ctg = (gid >> 9) & 63, s = gid >> 15;
  int k = s*32 + (l >> 4)*8 + j;
  int n = ctg*16 + (l & 15);
  int ug = n >> 7, c = n & 127;
  float v = Whh[((c >> 5)*256 + ug*32 + (c & 31))*256 + k];
  int fl = (s*64 + ctg)*512 + l*8 + j;
  u16 h = f2bf(v);
  out[fl] = h;
  out[262144 + fl] = f2bf(v - bf2f(h));
}

// WpT (1024x64) -> gate-permuted fragment-linear (K=64, N=1024)
__global__ void k_wpfl(const float* __restrict__ WpT, u16* __restrict__ out)
{
  int gid = blockIdx.x * 256 + threadIdx.x;   // 65536
  int j = gid & 7, l = (gid >> 3) & 63, ctg = (gid >> 9) & 63, s = gid >> 15;
  int k = s*32 + (l >> 4)*8 + j;              // < 64
  int n = ctg*16 + (l & 15);
  int ug = n >> 7, c = n & 127;
  float v = WpT[((c >> 5)*256 + ug*32 + (c & 31))*64 + k];
  int fl = (s*64 + ctg)*512 + l*8 + j;
  u16 h = f2bf(v);
  out[fl] = h;
  out[65536 + fl] = f2bf(v - bf2f(h));
}

// ---------------------------------------------------------------------------
// Encoder LSTM step via MFMA, weights in register B-frags (fragment-linear).
// grid = (CB/32, 8); block 256 = 4 waves; wave w owns gate w for units ug*32..+31.
// ---------------------------------------------------------------------------
__global__ __launch_bounds__(256,1) void k_enc_step(
    const float* __restrict__ x, const u16* __restrict__ whhFL,
    const u16* __restrict__ wpFL, const float* __restrict__ bpp,
    const u16* __restrict__ hpH, const u16* __restrict__ hpL,
    u16* __restrict__ hnH, u16* __restrict__ hnL,
    float* __restrict__ cst, float* __restrict__ enc, int t)
{
  __shared__ float G[4][32][32];
  const int tid = threadIdx.x, l = tid & 63, w = tid >> 6;
  const int lr = l & 15, lk = l >> 4;
  const int rb = blockIdx.x, ug = blockIdx.y;

  // ---- load persistent B fragments (Whh: 8 slabs x 2 ct x hi/lo; Wp: 2 x 2 x hi/lo)
  short8 whH[8][2], whL[8][2], wpH[2][2], wpL[2][2];
  #pragma unroll
  for (int s = 0; s < 8; ++s)
    #pragma unroll
    for (int ct = 0; ct < 2; ++ct) {
      int ctg = ug*8 + w*2 + ct;
      whH[s][ct] = *(const short8*)(whhFL + ((size_t)(s*64 + ctg))*512 + l*8);
      whL[s][ct] = *(const short8*)(whhFL + 262144 + ((size_t)(s*64 + ctg))*512 + l*8);
    }
  #pragma unroll
  for (int s = 0; s < 2; ++s)
    #pragma unroll
    for (int ct = 0; ct < 2; ++ct) {
      int ctg = ug*8 + w*2 + ct;
      wpH[s][ct] = *(const short8*)(wpFL + ((size_t)(s*64 + ctg))*512 + l*8);
      wpL[s][ct] = *(const short8*)(wpFL + 65536 + ((size_t)(s*64 + ctg))*512 + l*8);
    }

  f32x4 acc[2][2];
  #pragma unroll
  for (int rt = 0; rt < 2; ++rt)
    #pragma unroll
    for (int ct = 0; ct < 2; ++ct) acc[rt][ct] = (f32x4){0.f,0.f,0.f,0.f};

  // ---- h @ Whh'  (K = 256)
  #pragma unroll
  for (int s = 0; s < 8; ++s) {
    short8 ah[2], al[2];
    #pragma unroll
    for (int rt = 0; rt < 2; ++rt) {
      int row = rb*32 + rt*16 + lr;
      size_t off = (size_t)row*256 + s*32 + lk*8;
      ah[rt] = *(const short8*)(hpH + off);
      al[rt] = *(const short8*)(hpL + off);
    }
    #pragma unroll
    for (int ct = 0; ct < 2; ++ct)
      #pragma unroll
      for (int rt = 0; rt < 2; ++rt) {
        acc[rt][ct] = __builtin_amdgcn_mfma_f32_16x16x32_bf16(ah[rt], whH[s][ct], acc[rt][ct], 0,0,0);
        acc[rt][ct] = __builtin_amdgcn_mfma_f32_16x16x32_bf16(al[rt], whH[s][ct], acc[rt][ct], 0,0,0);
        acc[rt][ct] = __builtin_amdgcn_mfma_f32_16x16x32_bf16(ah[rt], whL[s][ct], acc[rt][ct], 0,0,0);
      }
  }
  // ---- x @ Wp'  (K = 64), split x on the fly
  #pragma unroll
  for (int s = 0; s < 2; ++s) {
    short8 ah[2], al[2];
    #pragma unroll
    for (int rt = 0; rt < 2; ++rt) {
      int row = rb*32 + rt*16 + lr;
      const float* xr = x + ((size_t)row*T_ + t)*DIN_ + s*32 + lk*8;
      float4 v0 = *(const float4*)(xr);
      float4 v1 = *(const float4*)(xr + 4);
      float vv[8] = {v0.x,v0.y,v0.z,v0.w,v1.x,v1.y,v1.z,v1.w};
      #pragma unroll
      for (int j = 0; j < 8; ++j) {
        u16 h = f2bf(vv[j]);
        ah[rt][j] = (short)h;
        al[rt][j] = (short)f2bf(vv[j] - bf2f(h));
      }
    }
    #pragma unroll
    for (int ct = 0; ct < 2; ++ct)
      #pragma unroll
      for (int rt = 0; rt < 2; ++rt) {
        acc[rt][ct] = __builtin_amdgcn_mfma_f32_16x16x32_bf16(ah[rt], wpH[s][ct], acc[rt][ct], 0,0,0);
        acc[rt][ct] = __builtin_amdgcn_mfma_f32_16x16x32_bf16(al[rt], wpH[s][ct], acc[rt][ct], 0,0,0);
        acc[rt][ct] = __builtin_amdgcn_mfma_f32_16x16x32_bf16(ah[rt], wpL[s][ct], acc[rt][ct], 0,0,0);
      }
  }

  // ---- gather gates, activations, c/h update
  #pragma unroll
  for (int rt = 0; rt < 2; ++rt)
    #pragma unroll
    for (int ct = 0; ct < 2; ++ct)
      #pragma unroll
      for (int g = 0; g < 4; ++g)
        G[w][rt*16 + lk*4 + g][ct*16 + lr] = acc[rt][ct][g];
  __syncthreads();

  const int uu = tid & 31, r0 = tid >> 5;
  const int nb = ug*128;
  #pragma unroll
  for (int rr = 0; rr < 4; ++rr) {
    int r = r0 + rr*8;
    float gi = G[0][r][uu] + bpp[nb + uu];
    float gf = G[1][r][uu] + bpp[nb + 32 + uu];
    float gg = G[2][r][uu] + bpp[nb + 64 + uu];
    float go = G[3][r][uu] + bpp[nb + 96 + uu];
    int b = rb*32 + r;
    int unit = ug*32 + uu;
    size_t idx = (size_t)b*256 + unit;
    float cn = sigm(gf)*cst[idx] + sigm(gi)*tanhf(gg);
    float hn = sigm(go)*tanhf(cn);
    cst[idx] = cn;
    u16 hh = f2bf(hn);
    hnH[idx] = hh;
    hnL[idx] = f2bf(hn - bf2f(hh));
    enc[((size_t)b*T_ + t)*256 + unit] = hn;
  }
}

// ---------------------------------------------------------------------------
// Fused multi-layer MLP: 128-row tile lives in LDS (u32 hi|lo, XOR-swizzled
// 16B chunks) across all L layers; weights streamed from global FL layout.
// IN: 0 = A0 fp32 rows; 1 = tanh(A0 + us[row>>9]).
// FIN: 0 = write fp32 C (last layer linear); 1 = dot with vWl -> e (all relu).
// block 512 thr = 8 waves (4 row-groups x 2 col-groups), 1 block/CU (128KB LDS).
// ---------------------------------------------------------------------------
template<int IN, int FIN>
__global__ __launch_bounds__(512,1) void k_mlp(
    const float* __restrict__ A0, const float* __restrict__ usp,
    const u16* __restrict__ wFL, const float* __restrict__ bs,
    const float* __restrict__ bl, float* __restrict__ Cout,
    float* __restrict__ eout, const float* __restrict__ vWl,
    const float* __restrict__ vbl, int L, int nbs)
{
  extern __shared__ u32 act[];   // [128][256] u32, chunk-swizzled
  const int tid = threadIdx.x, l = tid & 63, w = tid >> 6;
  const int rg = w >> 1, cg = w & 1;
  const int lr = l & 15, lk = l >> 4;
  const int wrow = rg*32;
  const long m0 = (long)blockIdx.x * 128;

  // ---- stage input
  for (int i = tid; i < 8192; i += 512) {        // 128 rows x 64 chunks
    int row = i >> 6, c16 = i & 63;
    long m = m0 + row;
    float4 v = *(const float4*)(A0 + m*256 + c16*4);
    if (IN == 1) {
      const float* ub = usp + (size_t)(m >> 9)*256;
      float4 u4 = *(const float4*)(ub + c16*4);
      v.x = tanhf(v.x + u4.x); v.y = tanhf(v.y + u4.y);
      v.z = tanhf(v.z + u4.z); v.w = tanhf(v.w + u4.w);
    }
    u32* dst = act + row*256 + (c16 ^ (row & 7))*4;
    ((uint4*)dst)[0] = (uint4){packhl(v.x), packhl(v.y), packhl(v.z), packhl(v.w)};
  }

  f32x4 acc[2][8];
  for (int lyr = 0; lyr < L; ++lyr) {
    __syncthreads();                              // act ready
    const u16* wb = wFL + (size_t)lyr*131072;
    #pragma unroll
    for (int rt = 0; rt < 2; ++rt)
      #pragma unroll
      for (int ct = 0; ct < 8; ++ct) acc[rt][ct] = (f32x4){0.f,0.f,0.f,0.f};

    for (int s = 0; s < 8; ++s) {
      short8 ah[2], al[2];
      #pragma unroll
      for (int rt = 0; rt < 2; ++rt) {
        int row = wrow + rt*16 + lr;
        int c16a = s*8 + lk*2;
        int q0 = c16a ^ (row & 7);
        const u32* base = act + row*256;
        uint4 d0 = *(const uint4*)(base + q0*4);
        uint4 d1 = *(const uint4*)(base + (q0 ^ 1)*4);
        u32 q[8] = {d0.x,d0.y,d0.z,d0.w,d1.x,d1.y,d1.z,d1.w};
        #pragma unroll
        for (int j = 0; j < 8; ++j) {
          ah[rt][j] = (short)(q[j] >> 16);
          al[rt][j] = (short)(q[j] & 0xffff);
        }
      }
      #pragma unroll
      for (int ct = 0; ct < 8; ++ct) {
        int ctg = cg*8 + ct;
        const u16* bfp = wb + ((size_t)(s*16 + ctg))*512 + l*8;
        short8 bh = *(const short8*)bfp;
        short8 blo = *(const short8*)(bfp + 65536);
        #pragma unroll
        for (int rt = 0; rt < 2; ++rt) {
          acc[rt][ct] = __builtin_amdgcn_mfma_f32_16x16x32_bf16(ah[rt], bh,  acc[rt][ct], 0,0,0);
          acc[rt][ct] = __builtin_amdgcn_mfma_f32_16x16x32_bf16(al[rt], bh,  acc[rt][ct], 0,0,0);
          acc[rt][ct] = __builtin_amdgcn_mfma_f32_16x16x32_bf16(ah[rt], blo, acc[rt][ct], 0,0,0);
        }
      }
    }
    // bias + relu
    const float* bptr = (lyr < nbs) ? (bs + lyr*256) : bl;
    const bool dorelu = (lyr < L-1) || (FIN == 1);
    #pragma unroll
    for (int ct = 0; ct < 8; ++ct) {
      float bv = bptr[cg*128 + ct*16 + lr];
      #pragma unroll
      for (int rt = 0; rt < 2; ++rt)
        #pragma unroll
        for (int g = 0; g < 4; ++g) {
          float xv = acc[rt][ct][g] + bv;
          acc[rt][ct][g] = dorelu ? fmaxf(xv, 0.f) : xv;
        }
    }
    if (lyr == L-1) break;
    __syncthreads();                              // all reads done
    #pragma unroll
    for (int ct = 0; ct < 8; ++ct) {
      int n = cg*128 + ct*16 + lr;
      #pragma unroll
      for (int rt = 0; rt < 2; ++rt)
        #pragma unroll
        for (int g = 0; g < 4; ++g) {
          int row = wrow + rt*16 + lk*4 + g;
          act[row*256 + (((n >> 2) ^ (row & 7))*4) + (n & 3)] = packhl(acc[rt][ct][g]);
        }
    }
  }

  if (FIN == 0) {
    #pragma unroll
    for (int ct = 0; ct < 8; ++ct) {
      int n = cg*128 + ct*16 + lr;
      #pragma unroll
      for (int rt = 0; rt < 2; ++rt)
        #pragma unroll
        for (int g = 0; g < 4; ++g) {
          long m = m0 + wrow + rt*16 + lk*4 + g;
          Cout[m*256 + n] = acc[rt][ct][g];
        }
    }
  } else {
    float part[2][4];
    #pragma unroll
    for (int rt = 0; rt < 2; ++rt)
      #pragma unroll
      for (int g = 0; g < 4; ++g) part[rt][g] = 0.f;
    #pragma unroll
    for (int ct = 0; ct < 8; ++ct) {
      float vw = vWl[cg*128 + ct*16 + lr];
      #pragma unroll
      for (int rt = 0; rt < 2; ++rt)
        #pragma unroll
        for (int g = 0; g < 4; ++g) part[rt][g] += acc[rt][ct][g] * vw;
    }
    #pragma unroll
    for (int o = 1; o < 16; o <<= 1)
      #pragma unroll
      for (int rt = 0; rt < 2; ++rt)
        #pragma unroll
        for (int g = 0; g < 4; ++g) part[rt][g] += __shfl_xor(part[rt][g], o, 64);
    __syncthreads();                              // act reads done; reuse as e_part
    float* ep = (float*)act;                      // [2][128]
    if ((l & 15) == 0) {
      #pragma unroll
      for (int rt = 0; rt < 2; ++rt)
        #pragma unroll
        for (int g = 0; g < 4; ++g)
          ep[cg*128 + wrow + rt*16 + lk*4 + g] = part[rt][g];
    }
    __syncthreads();
    for (int r = tid; r < 128; r += 512)
      eout[m0 + r] = ep[r] + ep[128 + r] + vbl[0];
  }
}

// ---------------------------------------------------------------------------
__global__ __launch_bounds__(256,4) void k_softmax(const float* __restrict__ e, float* __restrict__ a)
{
  __shared__ float red[8];
  const int b = blockIdx.x, tid = threadIdx.x;
  const int lane = tid & 63, w = tid >> 6;
  float v0 = e[b*512 + tid], v1 = e[b*512 + 256 + tid];
  float m = fmaxf(v0, v1);
  #pragma unroll
  for (int o = 32; o; o >>= 1) m = fmaxf(m, __shfl_xor(m, o, 64));
  if (!lane) red[w] = m;
  __syncthreads();
  m = fmaxf(fmaxf(red[0], red[1]), fmaxf(red[2], red[3]));
  float x0 = expf(v0 - m), x1 = expf(v1 - m);
  float sm = x0 + x1;
  #pragma unroll
  for (int o = 32; o; o >>= 1) sm += __shfl_xor(sm, o, 64);
  if (!lane) red[4 + w] = sm;
  __syncthreads();
  float inv = 1.f / (red[4] + red[5] + red[6] + red[7]);
  a[b*512 + tid]       = x0 * inv;
  a[b*512 + 256 + tid] = x1 * inv;
}

__global__ __launch_bounds__(256,2) void k_ctx(const float* __restrict__ a,
    const float* __restrict__ enc, float* __restrict__ ct)
{
  __shared__ float as[512];
  const int b = blockIdx.x, tid = threadIdx.x;
  as[tid] = a[b*512 + tid];
  as[256 + tid] = a[b*512 + 256 + tid];
  __syncthreads();
  float acc = 0.f;
  const float* ep = enc + (size_t)b*(T_*H_) + tid;
  #pragma unroll 8
  for (int t = 0; t < 512; ++t) acc += as[t] * ep[t*H_];
  ct[b*H_ + tid] = acc;
}

__global__ __launch_bounds__(256,2) void k_dec_cell(
    const float* __restrict__ ct, float* __restrict__ s, const float* __restrict__ dWt,
    const float* __restrict__ bih, const float* __restrict__ bhh,
    float* __restrict__ dec, int step)
{
  __shared__ float xt[8][516];
  const int tid = threadIdx.x;
  const int b0 = blockIdx.x * 8;
  for (int f = tid; f < 8*128; f += 256) {
    int bb = f >> 7, k4 = f & 127;
    float4 v = (k4 < 64) ? *(const float4*)(ct + (b0+bb)*H_ + k4*4)
                         : *(const float4*)(s  + (b0+bb)*H_ + (k4-64)*4);
    *(float4*)(&xt[bb][k4*4]) = v;
  }
  __syncthreads();
  const int u = tid;
  float ai[8], ag[8], ao[8];
  #pragma unroll
  for (int bb = 0; bb < 8; ++bb) { ai[bb]=0.f; ag[bb]=0.f; ao[bb]=0.f; }
  #pragma unroll 2
  for (int k = 0; k < 512; ++k) {
    float wi = dWt[k*768 + u];
    float wg = dWt[k*768 + 256 + u];
    float wo = dWt[k*768 + 512 + u];
    #pragma unroll
    for (int bb = 0; bb < 8; ++bb) {
      float xv = xt[bb][k];
      ai[bb] += xv*wi; ag[bb] += xv*wg; ao[bb] += xv*wo;
    }
  }
  float bi = bih[u]       + bhh[u];
  float bg = bih[512 + u] + bhh[512 + u];
  float bo = bih[768 + u] + bhh[768 + u];
  #pragma unroll
  for (int bb = 0; bb < 8; ++bb) {
    int b = b0 + bb;
    float cn = sigm(ai[bb] + bi) * tanhf(ag[bb] + bg);
    float hn = sigm(ao[bb] + bo) * tanhf(cn);
    s[b*H_ + u] = hn;
    dec[((size_t)b*OL_ + step)*H_ + u] = hn;
  }
}

__global__ __launch_bounds__(256,2) void k_outproj(
    const float* __restrict__ dec, const float* __restrict__ oW,
    const float* __restrict__ ob, float* __restrict__ out)
{
  const int tid = threadIdx.x;
  const int m0 = blockIdx.x * 16;
  const int d = tid & 63, rr = tid >> 6;
  float bv = ob[d];
  for (int p = 0; p < 4; ++p) {
    int m = m0 + p*4 + rr;
    const float* ar = dec + (size_t)m*H_;
    float acc = bv;
    #pragma unroll 4
    for (int k = 0; k < H_; ++k) acc += ar[k] * oW[k*64 + d];
    out[(size_t)m*64 + d] = acc;
  }
}

// ---------------------------------------------------------------------------
extern "C" void kernel_launch(void* const* d_in, const int* in_sizes, int n_in,
                              void* d_out, int out_size, void* d_ws, size_t ws_size,
                              hipStream_t stream)
{
  (void)in_sizes; (void)n_in;
  const float* x    = (const float*)d_in[0];
  const float* inW  = (const float*)d_in[1];
  const float* inb  = (const float*)d_in[2];
  const float* eWih = (const float*)d_in[3];
  const float* eWhh = (const float*)d_in[4];
  const float* ebih = (const float*)d_in[5];
  const float* ebhh = (const float*)d_in[6];
  const float* dWih = (const float*)d_in[7];
  const float* dbih = (const float*)d_in[9];
  const float* dbhh = (const float*)d_in[10];
  const float* wWs  = (const float*)d_in[11];
  const float* wbs  = (const float*)d_in[12];
  const float* wWl  = (const float*)d_in[13];
  const float* wbl  = (const float*)d_in[14];
  const float* uWs  = (const float*)d_in[15];
  const float* ubs  = (const float*)d_in[16];
  const float* uWl  = (const float*)d_in[17];
  const float* ubl  = (const float*)d_in[18];
  const float* vWs  = (const float*)d_in[19];
  const float* vbs  = (const float*)d_in[20];
  const float* vWl  = (const float*)d_in[21];
  const float* vbl  = (const float*)d_in[22];
  const float* oW   = (const float*)d_in[23];
  const float* ob   = (const float*)d_in[24];
  float* out = (float*)d_out;

  hipFuncSetAttribute((const void*)k_mlp<0,0>, hipFuncAttributeMaxDynamicSharedMemorySize, 131072);
  hipFuncSetAttribute((const void*)k_mlp<1,1>, hipFuncAttributeMaxDynamicSharedMemorySize, 131072);

  // footprint (floats): 2*cb*131072 + cb*4608 + fixed(~1.78M)
  const size_t avail = ws_size / 4;
  auto need = [](int cb) -> size_t {
    return 2ull*cb*T_*H_ + (size_t)cb*4608 + 1800000ull;
  };
  int CB = 512;
  while (CB > 128 && need(CB) > avail) CB >>= 1;
  if (need(CB) > avail) { hipMemsetAsync(d_out, 0, (size_t)out_size*4, stream); return; }

  float* wsf = (float*)d_ws;
  size_t o = 0;
  float* enc = wsf + o;  o += (size_t)CB*T_*H_;
  float* whs = wsf + o;  o += (size_t)CB*T_*H_;
  u16* hAH = (u16*)(wsf + o);             // 4 h planes + c + s contiguous for memset
  u16* hAL = hAH + (size_t)CB*256;
  u16* hBH = hAL + (size_t)CB*256;
  u16* hBL = hBH + (size_t)CB*256;        o += (size_t)CB*512;
  float* cst = wsf + o;  o += (size_t)CB*256;
  float* sbuf= wsf + o;  o += (size_t)CB*256;
  float* us  = wsf + o;  o += (size_t)CB*256;
  float* ctx = wsf + o;  o += (size_t)CB*256;
  float* dec = wsf + o;  o += (size_t)CB*2048;
  float* e   = wsf + o;  o += (size_t)CB*512;
  float* a   = wsf + o;  o += (size_t)CB*512;
  float* WpT = wsf + o;  o += 65536;
  float* bp  = wsf + o;  o += 1024;
  float* bpp = wsf + o;  o += 1024;
  float* dWt = wsf + o;  o += 393216;
  u16* whhFL = (u16*)(wsf + o);  o += 262144;   // 524288 u16
  u16* wpFL  = (u16*)(wsf + o);  o += 65536;    // 131072 u16
  u16* mlpFL = (u16*)(wsf + o);                 // 15 * 131072 u16

  // ---- weight preps (chunk-invariant)
  k_wpt<<<256, 256, 0, stream>>>(inW, eWih, WpT);
  k_bp <<<4,   256, 0, stream>>>(inb, eWih, ebih, ebhh, bp);
  k_bpp<<<4,   256, 0, stream>>>(bp, bpp);
  k_dwt<<<1536,256, 0, stream>>>(dWih, dWt);
  k_whhfl<<<1024,256,0,stream>>>(eWhh, whhFL);
  k_wpfl <<<256, 256,0,stream>>>(WpT, wpFL);
  const float* msrc[15] = { wWs, wWs+65536, wWs+2*65536, wWl,
                            uWs, uWs+65536, uWs+2*65536, uWl,
                            vWs, vWs+65536, vWs+2*65536, vWs+3*65536,
                            vWs+4*65536, vWs+5*65536, vWs+6*65536 };
  for (int i = 0; i < 15; ++i)
    k_wfl<<<256, 256, 0, stream>>>(msrc[i], mlpFL + (size_t)i*131072);

  const int gBig = CB * 4;        // (CB*T)/128
  const int gU   = CB / 128;

  for (int c0 = 0; c0 < B_; c0 += CB) {
    const float* xc = x + (size_t)c0*T_*DIN_;
    float* outc = out + (size_t)c0*OL_*DOUT_;

    // zero h planes + c + s (contiguous: 4*CB*512B + 2*CB*1024B)
    hipMemsetAsync(hAH, 0, (size_t)CB*4096, stream);

    // ---- encoder (MFMA step kernel, h ping-pong)
    for (int t = 0; t < T_; ++t) {
      const u16 *phH = (t & 1) ? hBH : hAH, *phL = (t & 1) ? hBL : hAL;
      u16 *pnH = (t & 1) ? hAH : hBH, *pnL = (t & 1) ? hAL : hBL;
      k_enc_step<<<dim3(CB/32, 8), 256, 0, stream>>>(xc, whhFL, wpFL, bpp,
                                                     phH, phL, pnH, pnL, cst, enc, t);
    }

    // ---- whs = w_mlp(enc)
    k_mlp<0,0><<<gBig, 512, 131072, stream>>>(enc, nullptr, mlpFL, wbs, wbl,
                                              whs, nullptr, nullptr, nullptr, 4, 3);

    // ---- decode loop
    for (int step = 0; step < OL_; ++step) {
      k_mlp<0,0><<<gU, 512, 131072, stream>>>(sbuf, nullptr, mlpFL + 4ull*131072, ubs, ubl,
                                              us, nullptr, nullptr, nullptr, 4, 3);
      k_mlp<1,1><<<gBig, 512, 131072, stream>>>(whs, us, mlpFL + 8ull*131072, vbs, nullptr,
                                                nullptr, e, vWl, vbl, 7, 7);
      k_softmax<<<CB, 256, 0, stream>>>(e, a);
      k_ctx    <<<CB, 256, 0, stream>>>(a, enc, ctx);
      k_dec_cell<<<CB/8, 256, 0, stream>>>(ctx, sbuf, dWt, dbih, dbhh, dec, step);
    }
    k_outproj<<<CB/2, 256, 0, stream>>>(dec, oW, ob, outc);
  }
}